// Round 3
// baseline (237.917 us; speedup 1.0000x reference)
//
#include <hip/hip_runtime.h>
#include <hip/hip_cooperative_groups.h>
#include <math.h>

namespace cg = cooperative_groups;

#define BATCH 8
#define CX 256
#define TC 512
#define CIN 768
#define HW_TOT 1024
#define NH 4
#define CHD 64

typedef __attribute__((ext_vector_type(8))) short short8;
typedef __attribute__((ext_vector_type(4))) short s4v;
typedef __attribute__((ext_vector_type(4))) float floatx4;
typedef __attribute__((ext_vector_type(4))) int int4v;

// softmax scale folded into Q: 0.125 * log2(e)
#define QSCALE 0.18033688f

// round-to-nearest-even f32 -> bf16
static __device__ __forceinline__ short f2bf(float f) {
    union { float f; unsigned u; } c; c.f = f;
    unsigned r = (c.u + 0x7fffu + ((c.u >> 16) & 1u)) >> 16;
    return (short)r;
}

// truncating pack of two f32 -> two bf16 in one int (lo in low half)
static __device__ __forceinline__ int pack_trunc(float lo, float hi) {
    union { float f; unsigned u; } L, H;
    L.f = lo; H.f = hi;
    return (int)((H.u & 0xffff0000u) | (L.u >> 16));
}

// ===========================================================================
// FUSED cooperative kernel. 32 KB LDS/block -> >=2 blocks/CU under any
// occupancy accounting (HIP often budgets 64 KB shared/CU for occupancy,
// which is what rejected round-2's 64 KB version). Grid-stride unit loops
// make it correct for grid 256 or 512.
// Phase A: GN stats (units 0-255) + Wt transpose (256-267). grid.sync
// Phase B: hnT transpose (0-255) + text contribution (256-639). grid.sync
// Phase C: qkv GEMM, 1536 units, BK=64 stride-72 internals (proven). grid.sync
// Phase D: flash attention, 512 units; Q frags direct from global (identical
//          values to the old LDS stage), K/V at stride-64 with row-XOR chunk
//          swizzle applied on BOTH write and read (bank-distribution
//          equivalent to the old stride-72 padding).
// ===========================================================================
__global__ __launch_bounds__(256, 2)
void fused_kernel(const float* __restrict__ x, const float* __restrict__ tf,
                  const float* __restrict__ gamma, const float* __restrict__ beta,
                  const float* __restrict__ W0, const float* __restrict__ b0,
                  const float* __restrict__ W1, const float* __restrict__ b1,
                  const float* __restrict__ W2, const float* __restrict__ b2,
                  float* __restrict__ scale, float* __restrict__ shift,
                  float* __restrict__ tc, short* __restrict__ Wt,
                  short* __restrict__ hnT, short* __restrict__ qb,
                  short* __restrict__ kb, short* __restrict__ vb,
                  float* __restrict__ out)
{
    __shared__ __align__(16) short SMs[16384];   // 32 KB, aliased per phase
    cg::grid_group grid = cg::this_grid();
    const int bx = blockIdx.x;
    const int gdx = gridDim.x;
    const int t = threadIdx.x;
    const int w = t >> 6, l = t & 63;
    const int l15 = l & 15, q = l >> 4;
    const int srow = t >> 2, sch = (t & 3) * 16;

    // ======================= Phase A: GN stats + Wt ========================
    for (int u = bx; u < 268; u += gdx) {
        __syncthreads();
        if (u < 256) {
            const int b = u >> 5;
            const int g = u & 31;
            if (u < 24) tc[u * 256 + t] = 0.f;   // zero 6144 floats for atomics

            float s = 0.f, ss = 0.f;
            #pragma unroll
            for (int rr = 0; rr < 6; rr++) {
                const int row = w * 6 + rr;          // 0..23
                const int cg_ = g * 24 + row;
                if (cg_ < CX) {
                    const float4* p = (const float4*)(x + ((size_t)b * CX + cg_) * HW_TOT);
                    #pragma unroll
                    for (int i = 0; i < 4; i++) {
                        float4 v = p[l + 64 * i];
                        s += v.x + v.y + v.z + v.w;
                        ss += v.x * v.x + v.y * v.y + v.z * v.z + v.w * v.w;
                    }
                } else {
                    float v = tf[b * TC + cg_ - CX];
                    s += 16.f * v;
                    ss += 16.f * v * v;
                }
            }
            #pragma unroll
            for (int d = 1; d < 64; d <<= 1) {
                s += __shfl_xor(s, d);
                ss += __shfl_xor(ss, d);
            }
            float* rs_ = (float*)SMs;
            float* rss_ = rs_ + 4;
            if (l == 0) { rs_[w] = s; rss_[w] = ss; }
            __syncthreads();
            const float S  = rs_[0] + rs_[1] + rs_[2] + rs_[3];
            const float SS = rss_[0] + rss_[1] + rss_[2] + rss_[3];
            const float inv_n = 1.f / (24 * 1024);
            const float mean = S * inv_n;
            const float var = SS * inv_n - mean * mean;
            const float r = rsqrtf(var + 1e-6f);
            if (t < 24) {
                int cg_ = g * 24 + t;
                float sc = gamma[cg_] * r;
                scale[b * CIN + cg_] = sc;
                shift[b * CIN + cg_] = beta[cg_] - mean * sc;
            }
        } else {
            int m = u - 256;
            int dg = (m % 3) * 256 + t;
            int which = dg >> 8, d = dg & 255;
            const float* Wm = (which == 0) ? W0 : (which == 1) ? W1 : W2;
            int c0base = (m / 3) * 64;
            for (int c0 = c0base; c0 < c0base + 64; c0 += 8) {
                short8 o;
                #pragma unroll
                for (int i = 0; i < 8; i++) o[i] = f2bf(Wm[(size_t)(c0 + i) * CX + d]);
                *(short8*)(Wt + (size_t)dg * CX + c0) = o;
            }
        }
    }
    grid.sync();

    // ================ Phase B: hnT transpose + text contribution ===========
    for (int u = bx; u < 640; u += gdx) {
        __syncthreads();
        if (u < 256) {
            int id = (u & 31) * 256 + t;
            int b = id >> 10;
            const float* xb = x + (size_t)b * CX * HW_TOT + (id & 1023);
            const float* scb = scale + b * CIN;
            const float* shb = shift + b * CIN;
            short* outp = hnT + (size_t)id * CX;
            int c0base = (u >> 5) * 32;
            for (int c0 = c0base; c0 < c0base + 32; c0 += 8) {
                short8 o;
                #pragma unroll
                for (int i = 0; i < 8; i++) {
                    float v = xb[(size_t)(c0 + i) * HW_TOT];
                    o[i] = f2bf(v * scb[c0 + i] + shb[c0 + i]);
                }
                *(short8*)(outp + c0) = o;
            }
        } else {
            // text contribution, K-split: handles 128 of the 512 text rows
            float* hs = (float*)SMs;                       // 128 floats
            float (*red)[64] = (float(*)[64])(hs + 128);   // 4x64 floats
            int m = u - 256;
            int ks = m & 3;
            int b = (m >> 2) & 7, dt = m >> 5;          // dt 0..11
            int which = dt >> 2, d0 = (dt & 3) * 64;
            const float* Wm = (which == 0) ? W0 : (which == 1) ? W1 : W2;
            if (t < 128) {
                int c = ks * 128 + t;
                hs[t] = tf[b * TC + c] * scale[b * CIN + CX + c] + shift[b * CIN + CX + c];
            }
            __syncthreads();
            int td = t & 63, tq = t >> 6;
            float acc = 0.f;
            const float* wp = Wm + (size_t)(CX + ks * 128 + tq * 32) * CX + d0 + td;
            #pragma unroll 8
            for (int c = 0; c < 32; c++)
                acc = fmaf(hs[tq * 32 + c], wp[(size_t)c * CX], acc);
            red[tq][td] = acc;
            __syncthreads();
            if (t < 64)
                atomicAdd(&tc[b * CIN + which * CX + d0 + t],
                          red[0][t] + red[1][t] + red[2][t] + red[3][t]);
        }
    }
    grid.sync();

    // ============== Phase C: QKV GEMM (1536 units, BK=64, proven) ==========
    {
        short* At = SMs;            // 64*72 shorts
        short* Bt = SMs + 4608;     // 64*72 shorts (total 18432 B)
        const int wm = w >> 1, wn = w & 1;

        for (int u = bx; u < 1536; u += gdx) {
            __syncthreads();
            const int b = u / 192;
            const int rem = u - b * 192;
            const int dt = rem >> 4;
            const int hw0 = (rem & 15) * 64;
            const int which = dt >> 2;
            const int col0 = (dt & 3) * 64;
            const int dg0 = which * 256 + col0;
            const bool OV = (which == 2);

            const short* gA = hnT + (size_t)(b * HW_TOT + hw0 + srow) * CX + sch;
            const short* gB = Wt + (size_t)(dg0 + srow) * CX + sch;

            floatx4 acc[2][2] = {};
            for (int k0 = 0; k0 < CX; k0 += 64) {
                __syncthreads();
                *(short8*)(At + srow * 72 + sch)     = *(const short8*)(gA + k0);
                *(short8*)(At + srow * 72 + sch + 8) = *(const short8*)(gA + k0 + 8);
                *(short8*)(Bt + srow * 72 + sch)     = *(const short8*)(gB + k0);
                *(short8*)(Bt + srow * 72 + sch + 8) = *(const short8*)(gB + k0 + 8);
                __syncthreads();
                const short* aB = OV ? Bt : At;
                const short* bB = OV ? At : Bt;
                #pragma unroll
                for (int kc = 0; kc < 2; kc++) {
                    short8 af[2], bf2[2];
                    #pragma unroll
                    for (int mt = 0; mt < 2; mt++)
                        af[mt] = *(const short8*)(aB + (wm * 32 + mt * 16 + l15) * 72 + kc * 32 + q * 8);
                    #pragma unroll
                    for (int nt = 0; nt < 2; nt++)
                        bf2[nt] = *(const short8*)(bB + (wn * 32 + nt * 16 + l15) * 72 + kc * 32 + q * 8);
                    #pragma unroll
                    for (int mt = 0; mt < 2; mt++)
                        #pragma unroll
                        for (int nt = 0; nt < 2; nt++)
                            acc[mt][nt] = __builtin_amdgcn_mfma_f32_16x16x32_bf16(
                                af[mt], bf2[nt], acc[mt][nt], 0, 0, 0);
                }
            }

            __syncthreads();
            const float* bias = (which == 0) ? b0 : (which == 1) ? b1 : b2;
            if (!OV) {
                const float qs = (which == 0) ? QSCALE : 1.0f;
                float cadd[2];
                #pragma unroll
                for (int nt = 0; nt < 2; nt++) {
                    int d = col0 + wn * 32 + nt * 16 + l15;
                    cadd[nt] = bias[d] + tc[b * CIN + which * CX + d];
                }
                #pragma unroll
                for (int mt = 0; mt < 2; mt++)
                    #pragma unroll
                    for (int rr = 0; rr < 4; rr++)
                        #pragma unroll
                        for (int nt = 0; nt < 2; nt++)
                            At[(wm * 32 + mt * 16 + q * 4 + rr) * 72 + wn * 32 + nt * 16 + l15]
                                = f2bf((acc[mt][nt][rr] + cadd[nt]) * qs);
            } else {
                #pragma unroll
                for (int mt = 0; mt < 2; mt++)
                    #pragma unroll
                    for (int rr = 0; rr < 4; rr++) {
                        int d = col0 + wm * 32 + mt * 16 + q * 4 + rr;
                        float radd = bias[d] + tc[b * CIN + 2 * CX + d];
                        #pragma unroll
                        for (int nt = 0; nt < 2; nt++)
                            At[(wm * 32 + mt * 16 + q * 4 + rr) * 72 + wn * 32 + nt * 16 + l15]
                                = f2bf(acc[mt][nt][rr] + radd);
                    }
            }
            __syncthreads();
            short8 v0 = *(const short8*)(At + srow * 72 + sch);
            short8 v1 = *(const short8*)(At + srow * 72 + sch + 8);
            if (!OV) {
                short* outp = (which == 0) ? qb : kb;
                size_t off = (size_t)(b * HW_TOT + hw0 + srow) * CX + col0 + sch;
                *(short8*)(outp + off) = v0;
                *(short8*)(outp + off + 8) = v1;
            } else {
                size_t off = (size_t)(b * CX + col0 + srow) * HW_TOT + hw0 + sch;
                *(short8*)(vb + off) = v0;
                *(short8*)(vb + off + 8) = v1;
            }
        }
    }
    grid.sync();

    // ======================= Phase D: flash attention ======================
    {
        // K halves at SMs + jh*4096 shorts; V halves at SMs + 8192 + jh*4096.
        // stride 64 shorts/row; 16B chunk c of row r stored at (c ^ (r&7)).
        const int pair = w >> 1, jh = w & 1;
        const int sw7 = srow & 7;
        const int kc0 = (t & 3) * 2;                 // chunk pair staged (K)
        const int vpos0 = ((sch >> 5) << 5) + ((sch >> 4) & 1) * 4;
        const int vc0 = vpos0 >> 3;                  // 0 or 4
        const int voff = vpos0 & 7;                  // 0 or 4 (shorts)

        union { int4v i; short8 s; } ones;
        ones.i[0] = 0x3f803f80; ones.i[1] = 0x3f803f80;
        ones.i[2] = 0x3f803f80; ones.i[3] = 0x3f803f80;

        for (int u = bx; u < 512; u += gdx) {
            __syncthreads();
            const int qt = u & 15, bh = u >> 4;
            const int b = bh >> 2, h = bh & 3;
            const int hw0 = qt * 64;

            // Q fragments direct from global (identical values to LDS stage)
            short8 aq[2][2];
            #pragma unroll
            for (int g = 0; g < 2; g++) {
                const short* gq = qb + (size_t)(b * HW_TOT + hw0 + pair * 32 + g * 16 + l15) * CX
                                  + h * CHD + q * 8;
                aq[g][0] = *(const short8*)gq;
                aq[g][1] = *(const short8*)(gq + 32);
            }

            // stage first tile of EACH j-half
            short8 pk[2][2], pv[2][2];
            #pragma unroll
            for (int s = 0; s < 2; s++) {
                const int j0 = s * 512;
                const short* gk = kb + (size_t)(b * HW_TOT + j0 + srow) * CX + h * CHD + sch;
                pk[s][0] = *(const short8*)gk;
                pk[s][1] = *(const short8*)(gk + 8);
                const short* gv = vb + (size_t)(b * CX + h * CHD + srow) * HW_TOT + j0 + sch;
                pv[s][0] = *(const short8*)gv;
                pv[s][1] = *(const short8*)(gv + 8);
            }
            #pragma unroll
            for (int s = 0; s < 2; s++) {
                short* Ksp = SMs + s * 4096 + srow * 64;
                short* Vsp = SMs + 8192 + s * 4096 + srow * 64;
                *(short8*)(Ksp + ((kc0    ) ^ sw7) * 8) = pk[s][0];
                *(short8*)(Ksp + ((kc0 + 1) ^ sw7) * 8) = pk[s][1];
                *(s4v*)(Vsp + ((vc0    ) ^ sw7) * 8 + voff) = __builtin_shufflevector(pv[s][0], pv[s][0], 0, 1, 2, 3);
                *(s4v*)(Vsp + ((vc0 + 1) ^ sw7) * 8 + voff) = __builtin_shufflevector(pv[s][0], pv[s][0], 4, 5, 6, 7);
                *(s4v*)(Vsp + ((vc0 + 2) ^ sw7) * 8 + voff) = __builtin_shufflevector(pv[s][1], pv[s][1], 0, 1, 2, 3);
                *(s4v*)(Vsp + ((vc0 + 3) ^ sw7) * 8 + voff) = __builtin_shufflevector(pv[s][1], pv[s][1], 4, 5, 6, 7);
            }
            __syncthreads();

            floatx4 oacc[2][4] = {};
            floatx4 lacc[2] = {};
            const short* Kc = SMs + jh * 4096;
            const short* Vc = SMs + 8192 + jh * 4096;

            for (int jj = 0; jj < 8; jj++) {
                if (jj < 7) {   // prefetch next tile of each half into regs
                    #pragma unroll
                    for (int s = 0; s < 2; s++) {
                        const int j0 = s * 512 + (jj + 1) * 64;
                        const short* gk = kb + (size_t)(b * HW_TOT + j0 + srow) * CX + h * CHD + sch;
                        pk[s][0] = *(const short8*)gk;
                        pk[s][1] = *(const short8*)(gk + 8);
                        const short* gv = vb + (size_t)(b * CX + h * CHD + srow) * HW_TOT + j0 + sch;
                        pv[s][0] = *(const short8*)gv;
                        pv[s][1] = *(const short8*)(gv + 8);
                    }
                }

                // S^T = K . Q'^T
                floatx4 sacc[2][4] = {};
                __builtin_amdgcn_s_setprio(1);
                #pragma unroll
                for (int nt = 0; nt < 4; nt++) {
                    const int r = nt * 16 + l15;
                    short8 kf0 = *(const short8*)(Kc + r * 64 + ((q    ) ^ (r & 7)) * 8);
                    short8 kf1 = *(const short8*)(Kc + r * 64 + ((4 + q) ^ (r & 7)) * 8);
                    #pragma unroll
                    for (int g = 0; g < 2; g++) {
                        sacc[g][nt] = __builtin_amdgcn_mfma_f32_16x16x32_bf16(kf0, aq[g][0], sacc[g][nt], 0, 0, 0);
                        sacc[g][nt] = __builtin_amdgcn_mfma_f32_16x16x32_bf16(kf1, aq[g][1], sacc[g][nt], 0, 0, 0);
                    }
                }
                __builtin_amdgcn_s_setprio(0);

                // p = exp2(s'); truncating pack into B-operand registers
                union { int4v i; short8 s; } uu[2][2];
                #pragma unroll
                for (int g = 0; g < 2; g++)
                    #pragma unroll
                    for (int nt = 0; nt < 4; nt++) {
                        float e0 = exp2f(sacc[g][nt][0]);
                        float e1 = exp2f(sacc[g][nt][1]);
                        float e2 = exp2f(sacc[g][nt][2]);
                        float e3 = exp2f(sacc[g][nt][3]);
                        uu[g][nt >> 1].i[(nt & 1) * 2]     = pack_trunc(e0, e1);
                        uu[g][nt >> 1].i[(nt & 1) * 2 + 1] = pack_trunc(e2, e3);
                    }

                __builtin_amdgcn_s_setprio(1);
                // l += 1^T . P
                #pragma unroll
                for (int g = 0; g < 2; g++) {
                    lacc[g] = __builtin_amdgcn_mfma_f32_16x16x32_bf16(ones.s, uu[g][0].s, lacc[g], 0, 0, 0);
                    lacc[g] = __builtin_amdgcn_mfma_f32_16x16x32_bf16(ones.s, uu[g][1].s, lacc[g], 0, 0, 0);
                }

                // O^T += V^T . P
                #pragma unroll
                for (int ct = 0; ct < 4; ct++) {
                    const int rv = ct * 16 + l15;
                    #pragma unroll
                    for (int kcc = 0; kcc < 2; kcc++) {
                        short8 vf = *(const short8*)(Vc + rv * 64 + ((kcc * 4 + q) ^ (rv & 7)) * 8);
                        #pragma unroll
                        for (int g = 0; g < 2; g++)
                            oacc[g][ct] = __builtin_amdgcn_mfma_f32_16x16x32_bf16(
                                vf, uu[g][kcc].s, oacc[g][ct], 0, 0, 0);
                    }
                }
                __builtin_amdgcn_s_setprio(0);

                if (jj < 7) {
                    __syncthreads();   // all waves done reading current tiles
                    #pragma unroll
                    for (int s = 0; s < 2; s++) {
                        short* Ksp = SMs + s * 4096 + srow * 64;
                        short* Vsp = SMs + 8192 + s * 4096 + srow * 64;
                        *(short8*)(Ksp + ((kc0    ) ^ sw7) * 8) = pk[s][0];
                        *(short8*)(Ksp + ((kc0 + 1) ^ sw7) * 8) = pk[s][1];
                        *(s4v*)(Vsp + ((vc0    ) ^ sw7) * 8 + voff) = __builtin_shufflevector(pv[s][0], pv[s][0], 0, 1, 2, 3);
                        *(s4v*)(Vsp + ((vc0 + 1) ^ sw7) * 8 + voff) = __builtin_shufflevector(pv[s][0], pv[s][0], 4, 5, 6, 7);
                        *(s4v*)(Vsp + ((vc0 + 2) ^ sw7) * 8 + voff) = __builtin_shufflevector(pv[s][1], pv[s][1], 0, 1, 2, 3);
                        *(s4v*)(Vsp + ((vc0 + 3) ^ sw7) * 8 + voff) = __builtin_shufflevector(pv[s][1], pv[s][1], 4, 5, 6, 7);
                    }
                    __syncthreads();   // writes visible
                }
            }

            // cross-half combine through LDS (fixed-max => pure addition)
            __syncthreads();
            float* Of = (float*)SMs;                 // [qi][c] stride 68 (17408 B)
            float* Lf = ((float*)SMs) + 64 * 68;     // [qi] (256 B)
            if (jh == 1) {
                #pragma unroll
                for (int g = 0; g < 2; g++) {
                    int qi = pair * 32 + g * 16 + l15;
                    #pragma unroll
                    for (int ct = 0; ct < 4; ct++)
                        *(floatx4*)&Of[qi * 68 + ct * 16 + q * 4] = oacc[g][ct];
                    if (q == 0) Lf[qi] = lacc[g][0];
                }
            }
            __syncthreads();
            if (jh == 0) {
                #pragma unroll
                for (int g = 0; g < 2; g++) {
                    int qi = pair * 32 + g * 16 + l15;
                    const float rinv = 1.f / (lacc[g][0] + Lf[qi]);
                    #pragma unroll
                    for (int ct = 0; ct < 4; ct++) {
                        floatx4 po = *(const floatx4*)&Of[qi * 68 + ct * 16 + q * 4];
                        #pragma unroll
                        for (int r = 0; r < 4; r++) {
                            int c = h * CHD + ct * 16 + q * 4 + r;
                            size_t idx = (size_t)(b * CX + c) * HW_TOT + hw0 + qi;
                            out[idx] = x[idx] + (oacc[g][ct][r] + po[r]) * rinv;
                        }
                    }
                }
            }
        }
    }
}

// ===========================================================================
// FALLBACK: the proven 4-kernel pipeline (round-1, passed). Launched only if
// the cooperative launch is rejected.
// ===========================================================================
__global__ __launch_bounds__(256)
void gn_kernel(const float* __restrict__ x, const float* __restrict__ tf,
               const float* __restrict__ gamma, const float* __restrict__ beta,
               float* __restrict__ scale, float* __restrict__ shift,
               float* __restrict__ tc) {
    const int b = blockIdx.x >> 5;
    const int g = blockIdx.x & 31;
    const int t = threadIdx.x;
    const int w = t >> 6, lane = t & 63;
    if (blockIdx.x < 24) tc[blockIdx.x * 256 + t] = 0.f;

    float s = 0.f, ss = 0.f;
    #pragma unroll
    for (int rr = 0; rr < 6; rr++) {
        const int row = w * 6 + rr;
        const int cg = g * 24 + row;
        if (cg < CX) {
            const float4* p = (const float4*)(x + ((size_t)b * CX + cg) * HW_TOT);
            #pragma unroll
            for (int i = 0; i < 4; i++) {
                float4 v = p[lane + 64 * i];
                s += v.x + v.y + v.z + v.w;
                ss += v.x * v.x + v.y * v.y + v.z * v.z + v.w * v.w;
            }
        } else {
            float v = tf[b * TC + cg - CX];
            s += 16.f * v;
            ss += 16.f * v * v;
        }
    }
    #pragma unroll
    for (int d = 1; d < 64; d <<= 1) {
        s += __shfl_xor(s, d);
        ss += __shfl_xor(ss, d);
    }
    __shared__ float rs_[4], rss_[4];
    if (lane == 0) { rs_[w] = s; rss_[w] = ss; }
    __syncthreads();
    const float S  = rs_[0] + rs_[1] + rs_[2] + rs_[3];
    const float SS = rss_[0] + rss_[1] + rss_[2] + rss_[3];
    const float inv_n = 1.f / (24 * 1024);
    const float mean = S * inv_n;
    const float var = SS * inv_n - mean * mean;
    const float r = rsqrtf(var + 1e-6f);
    if (t < 24) {
        int cg = g * 24 + t;
        float sc = gamma[cg] * r;
        scale[b * CIN + cg] = sc;
        shift[b * CIN + cg] = beta[cg] - mean * sc;
    }
}

__global__ __launch_bounds__(256)
void prep_kernel(const float* __restrict__ x, const float* __restrict__ tf,
                 const float* __restrict__ scale, const float* __restrict__ shift,
                 const float* __restrict__ W0, const float* __restrict__ W1,
                 const float* __restrict__ W2,
                 short* __restrict__ hnT, short* __restrict__ Wt,
                 float* __restrict__ tc) {
    __shared__ float hs[128];
    __shared__ float red[4][64];
    const int bx = blockIdx.x;
    const int t = threadIdx.x;
    if (bx < 256) {
        int id = (bx & 31) * 256 + t;
        int b = id >> 10;
        const float* xb = x + (size_t)b * CX * HW_TOT + (id & 1023);
        const float* scb = scale + b * CIN;
        const float* shb = shift + b * CIN;
        short* outp = hnT + (size_t)id * CX;
        int c0base = (bx >> 5) * 32;
        for (int c0 = c0base; c0 < c0base + 32; c0 += 8) {
            short8 o;
            #pragma unroll
            for (int i = 0; i < 8; i++) {
                float v = xb[(size_t)(c0 + i) * HW_TOT];
                o[i] = f2bf(v * scb[c0 + i] + shb[c0 + i]);
            }
            *(short8*)(outp + c0) = o;
        }
    } else if (bx < 268) {
        int m = bx - 256;
        int dg = (m % 3) * 256 + t;
        int which = dg >> 8, d = dg & 255;
        const float* Wm = (which == 0) ? W0 : (which == 1) ? W1 : W2;
        int c0base = (m / 3) * 64;
        for (int c0 = c0base; c0 < c0base + 64; c0 += 8) {
            short8 o;
            #pragma unroll
            for (int i = 0; i < 8; i++) o[i] = f2bf(Wm[(size_t)(c0 + i) * CX + d]);
            *(short8*)(Wt + (size_t)dg * CX + c0) = o;
        }
    } else {
        int m = bx - 268;
        int ks = m & 3;
        int b = (m >> 2) & 7, dt = m >> 5;
        int which = dt >> 2, d0 = (dt & 3) * 64;
        const float* Wm = (which == 0) ? W0 : (which == 1) ? W1 : W2;
        if (t < 128) {
            int c = ks * 128 + t;
            hs[t] = tf[b * TC + c] * scale[b * CIN + CX + c] + shift[b * CIN + CX + c];
        }
        __syncthreads();
        int td = t & 63, tq = t >> 6;
        float acc = 0.f;
        const float* wp = Wm + (size_t)(CX + ks * 128 + tq * 32) * CX + d0 + td;
        #pragma unroll 8
        for (int c = 0; c < 32; c++)
            acc = fmaf(hs[tq * 32 + c], wp[(size_t)c * CX], acc);
        red[tq][td] = acc;
        __syncthreads();
        if (t < 64)
            atomicAdd(&tc[b * CIN + which * CX + d0 + t],
                      red[0][t] + red[1][t] + red[2][t] + red[3][t]);
    }
}

__global__ __launch_bounds__(256, 2)
void qkv_gemm(const short* __restrict__ hnT, const short* __restrict__ Wt,
              const float* __restrict__ tc,
              const float* __restrict__ b0, const float* __restrict__ b1,
              const float* __restrict__ b2,
              short* __restrict__ qb, short* __restrict__ kb, short* __restrict__ vb) {
    const int hw0 = blockIdx.x * 64, dt = blockIdx.y, b = blockIdx.z;
    const int which = dt >> 2;
    const int col0 = (dt & 3) * 64;
    const int dg0 = which * 256 + col0;
    const bool OV = (which == 2);

    __shared__ short At[64 * 256];
    __shared__ short Bt[64 * 256];

    const int t = threadIdx.x;
    const int w = t >> 6, l = t & 63;
    const int wm = w >> 1, wn = w & 1;
    const int l15 = l & 15, q = l >> 4;
    const int srow = t >> 2;
    const int cbase = (t & 3) * 8;
    const int sw = srow & 7;

    const short* gA = hnT + (size_t)(b * HW_TOT + hw0 + srow) * CX + cbase * 8;
    const short* gB = Wt + (size_t)(dg0 + srow) * CX + cbase * 8;

    short8 ra[8], rb[8];
    #pragma unroll
    for (int i = 0; i < 8; i++) ra[i] = *(const short8*)(gA + i * 8);
    #pragma unroll
    for (int i = 0; i < 8; i++) rb[i] = *(const short8*)(gB + i * 8);
    short* wA = At + srow * 256;
    short* wB = Bt + srow * 256;
    #pragma unroll
    for (int i = 0; i < 8; i++) *(short8*)(wA + ((cbase + i) ^ sw) * 8) = ra[i];
    #pragma unroll
    for (int i = 0; i < 8; i++) *(short8*)(wB + ((cbase + i) ^ sw) * 8) = rb[i];
    __syncthreads();

    const short* aB = OV ? Bt : At;
    const short* bB = OV ? At : Bt;

    floatx4 acc[2][2] = {};
    __builtin_amdgcn_s_setprio(1);
    #pragma unroll
    for (int kc = 0; kc < 8; kc++) {
        short8 af[2], bf2[2];
        #pragma unroll
        for (int mt = 0; mt < 2; mt++) {
            const int rr = wm * 32 + mt * 16 + l15;
            af[mt] = *(const short8*)(aB + rr * 256 + ((kc * 4 + q) ^ (rr & 7)) * 8);
        }
        #pragma unroll
        for (int nt = 0; nt < 2; nt++) {
            const int rr = wn * 32 + nt * 16 + l15;
            bf2[nt] = *(const short8*)(bB + rr * 256 + ((kc * 4 + q) ^ (rr & 7)) * 8);
        }
        #pragma unroll
        for (int mt = 0; mt < 2; mt++)
            #pragma unroll
            for (int nt = 0; nt < 2; nt++)
                acc[mt][nt] = __builtin_amdgcn_mfma_f32_16x16x32_bf16(
                    af[mt], bf2[nt], acc[mt][nt], 0, 0, 0);
    }
    __builtin_amdgcn_s_setprio(0);

    __syncthreads();
    const float* bias = (which == 0) ? b0 : (which == 1) ? b1 : b2;
    if (!OV) {
        const float qs = (which == 0) ? QSCALE : 1.0f;
        float cadd[2];
        #pragma unroll
        for (int nt = 0; nt < 2; nt++) {
            int d = col0 + wn * 32 + nt * 16 + l15;
            cadd[nt] = bias[d] + tc[b * CIN + which * CX + d];
        }
        #pragma unroll
        for (int mt = 0; mt < 2; mt++)
            #pragma unroll
            for (int rr = 0; rr < 4; rr++)
                #pragma unroll
                for (int nt = 0; nt < 2; nt++)
                    At[(wm * 32 + mt * 16 + q * 4 + rr) * 72 + wn * 32 + nt * 16 + l15]
                        = f2bf((acc[mt][nt][rr] + cadd[nt]) * qs);
    } else {
        #pragma unroll
        for (int mt = 0; mt < 2; mt++)
            #pragma unroll
            for (int rr = 0; rr < 4; rr++) {
                int d = col0 + wm * 32 + mt * 16 + q * 4 + rr;
                float radd = bias[d] + tc[b * CIN + 2 * CX + d];
                #pragma unroll
                for (int nt = 0; nt < 2; nt++)
                    At[(wm * 32 + mt * 16 + q * 4 + rr) * 72 + wn * 32 + nt * 16 + l15]
                        = f2bf(acc[mt][nt][rr] + radd);
            }
    }
    __syncthreads();
    const int sch2 = (t & 3) * 16;
    short8 v0 = *(const short8*)(At + srow * 72 + sch2);
    short8 v1 = *(const short8*)(At + srow * 72 + sch2 + 8);
    if (!OV) {
        short* outp = (which == 0) ? qb : kb;
        size_t off = (size_t)(b * HW_TOT + hw0 + srow) * CX + col0 + sch2;
        *(short8*)(outp + off) = v0;
        *(short8*)(outp + off + 8) = v1;
    } else {
        size_t off = (size_t)(b * CX + col0 + srow) * HW_TOT + hw0 + sch2;
        *(short8*)(vb + off) = v0;
        *(short8*)(vb + off + 8) = v1;
    }
}

__global__ __launch_bounds__(256, 3)
void attn_kernel(const short* __restrict__ qb, const short* __restrict__ kb,
                 const short* __restrict__ vb, const float* __restrict__ x,
                 float* __restrict__ out) {
    const int qt = blockIdx.x, bh = blockIdx.y;
    const int b = bh >> 2, h = bh & 3;
    const int hw0 = qt * 64;

    __shared__ short Qs[64 * 72];
    __shared__ short Ks[2][64 * 72];
    __shared__ short Vs[2][64 * 72];

    const int t = threadIdx.x;
    const int w = t >> 6, l = t & 63;
    const int pair = w >> 1, jh = w & 1;
    const int l15 = l & 15, q = l >> 4;
    const int srow = t >> 2, sch = (t & 3) * 16;
    const int vpos0 = ((sch >> 5) << 5) + ((sch >> 4) & 1) * 4;

    {
        const short* gq = qb + (size_t)(b * HW_TOT + hw0 + srow) * CX + h * CHD + sch;
        *(short8*)(Qs + srow * 72 + sch)     = *(const short8*)gq;
        *(short8*)(Qs + srow * 72 + sch + 8) = *(const short8*)(gq + 8);
    }

    short8 pk[2][2], pv[2][2];
    #pragma unroll
    for (int s = 0; s < 2; s++) {
        const int j0 = s * 512;
        const short* gk = kb + (size_t)(b * HW_TOT + j0 + srow) * CX + h * CHD + sch;
        pk[s][0] = *(const short8*)gk;
        pk[s][1] = *(const short8*)(gk + 8);
        const short* gv = vb + (size_t)(b * CX + h * CHD + srow) * HW_TOT + j0 + sch;
        pv[s][0] = *(const short8*)gv;
        pv[s][1] = *(const short8*)(gv + 8);
    }
    #pragma unroll
    for (int s = 0; s < 2; s++) {
        *(short8*)(Ks[s] + srow * 72 + sch)     = pk[s][0];
        *(short8*)(Ks[s] + srow * 72 + sch + 8) = pk[s][1];
        short* vrow = Vs[s] + srow * 72 + vpos0;
        *(s4v*)(vrow)      = __builtin_shufflevector(pv[s][0], pv[s][0], 0, 1, 2, 3);
        *(s4v*)(vrow + 8)  = __builtin_shufflevector(pv[s][0], pv[s][0], 4, 5, 6, 7);
        *(s4v*)(vrow + 16) = __builtin_shufflevector(pv[s][1], pv[s][1], 0, 1, 2, 3);
        *(s4v*)(vrow + 24) = __builtin_shufflevector(pv[s][1], pv[s][1], 4, 5, 6, 7);
    }
    __syncthreads();

    short8 aq[2][2];
    #pragma unroll
    for (int g = 0; g < 2; g++) {
        aq[g][0] = *(const short8*)(Qs + (pair * 32 + g * 16 + l15) * 72 + q * 8);
        aq[g][1] = *(const short8*)(Qs + (pair * 32 + g * 16 + l15) * 72 + 32 + q * 8);
    }

    union { int4v i; short8 s; } ones;
    ones.i[0] = 0x3f803f80; ones.i[1] = 0x3f803f80;
    ones.i[2] = 0x3f803f80; ones.i[3] = 0x3f803f80;

    floatx4 oacc[2][4] = {};
    floatx4 lacc[2] = {};
    const short* Kc = Ks[jh];
    const short* Vc = Vs[jh];

    for (int jj = 0; jj < 8; jj++) {
        if (jj < 7) {
            #pragma unroll
            for (int s = 0; s < 2; s++) {
                const int j0 = s * 512 + (jj + 1) * 64;
                const short* gk = kb + (size_t)(b * HW_TOT + j0 + srow) * CX + h * CHD + sch;
                pk[s][0] = *(const short8*)gk;
                pk[s][1] = *(const short8*)(gk + 8);
                const short* gv = vb + (size_t)(b * CX + h * CHD + srow) * HW_TOT + j0 + sch;
                pv[s][0] = *(const short8*)gv;
                pv[s][1] = *(const short8*)(gv + 8);
            }
        }

        floatx4 sacc[2][4] = {};
        __builtin_amdgcn_s_setprio(1);
        #pragma unroll
        for (int nt = 0; nt < 4; nt++) {
            short8 kf0 = *(const short8*)(Kc + (nt * 16 + l15) * 72 + q * 8);
            short8 kf1 = *(const short8*)(Kc + (nt * 16 + l15) * 72 + 32 + q * 8);
            #pragma unroll
            for (int g = 0; g < 2; g++) {
                sacc[g][nt] = __builtin_amdgcn_mfma_f32_16x16x32_bf16(kf0, aq[g][0], sacc[g][nt], 0, 0, 0);
                sacc[g][nt] = __builtin_amdgcn_mfma_f32_16x16x32_bf16(kf1, aq[g][1], sacc[g][nt], 0, 0, 0);
            }
        }
        __builtin_amdgcn_s_setprio(0);

        union { int4v i; short8 s; } u[2][2];
        #pragma unroll
        for (int g = 0; g < 2; g++)
            #pragma unroll
            for (int nt = 0; nt < 4; nt++) {
                float e0 = exp2f(sacc[g][nt][0]);
                float e1 = exp2f(sacc[g][nt][1]);
                float e2 = exp2f(sacc[g][nt][2]);
                float e3 = exp2f(sacc[g][nt][3]);
                u[g][nt >> 1].i[(nt & 1) * 2]     = pack_trunc(e0, e1);
                u[g][nt >> 1].i[(nt & 1) * 2 + 1] = pack_trunc(e2, e3);
            }

        __builtin_amdgcn_s_setprio(1);
        #pragma unroll
        for (int g = 0; g < 2; g++) {
            lacc[g] = __builtin_amdgcn_mfma_f32_16x16x32_bf16(ones.s, u[g][0].s, lacc[g], 0, 0, 0);
            lacc[g] = __builtin_amdgcn_mfma_f32_16x16x32_bf16(ones.s, u[g][1].s, lacc[g], 0, 0, 0);
        }

        #pragma unroll
        for (int ct = 0; ct < 4; ct++) {
            const short* vr = Vc + (ct * 16 + l15) * 72;
            #pragma unroll
            for (int kcc = 0; kcc < 2; kcc++) {
                short8 vf = *(const short8*)(vr + kcc * 32 + q * 8);
                #pragma unroll
                for (int g = 0; g < 2; g++)
                    oacc[g][ct] = __builtin_amdgcn_mfma_f32_16x16x32_bf16(
                        vf, u[g][kcc].s, oacc[g][ct], 0, 0, 0);
            }
        }
        __builtin_amdgcn_s_setprio(0);

        if (jj < 7) {
            __syncthreads();
            #pragma unroll
            for (int s = 0; s < 2; s++) {
                *(short8*)(Ks[s] + srow * 72 + sch)     = pk[s][0];
                *(short8*)(Ks[s] + srow * 72 + sch + 8) = pk[s][1];
                short* vrow = Vs[s] + srow * 72 + vpos0;
                *(s4v*)(vrow)      = __builtin_shufflevector(pv[s][0], pv[s][0], 0, 1, 2, 3);
                *(s4v*)(vrow + 8)  = __builtin_shufflevector(pv[s][0], pv[s][0], 4, 5, 6, 7);
                *(s4v*)(vrow + 16) = __builtin_shufflevector(pv[s][1], pv[s][1], 0, 1, 2, 3);
                *(s4v*)(vrow + 24) = __builtin_shufflevector(pv[s][1], pv[s][1], 4, 5, 6, 7);
            }
            __syncthreads();
        }
    }

    __syncthreads();
    float* Of = (float*)Ks;
    float* Lf = (float*)Vs;
    if (jh == 1) {
        #pragma unroll
        for (int g = 0; g < 2; g++) {
            int qi = pair * 32 + g * 16 + l15;
            #pragma unroll
            for (int ct = 0; ct < 4; ct++)
                *(floatx4*)&Of[qi * 68 + ct * 16 + q * 4] = oacc[g][ct];
            if (q == 0) Lf[qi] = lacc[g][0];
        }
    }
    __syncthreads();
    if (jh == 0) {
        #pragma unroll
        for (int g = 0; g < 2; g++) {
            int qi = pair * 32 + g * 16 + l15;
            const float rinv = 1.f / (lacc[g][0] + Lf[qi]);
            #pragma unroll
            for (int ct = 0; ct < 4; ct++) {
                floatx4 po = *(const floatx4*)&Of[qi * 68 + ct * 16 + q * 4];
                #pragma unroll
                for (int r = 0; r < 4; r++) {
                    int c = h * CHD + ct * 16 + q * 4 + r;
                    size_t idx = (size_t)(b * CX + c) * HW_TOT + hw0 + qi;
                    out[idx] = x[idx] + (oacc[g][ct][r] + po[r]) * rinv;
                }
            }
        }
    }
}

// ---------------------------------------------------------------------------
extern "C" void kernel_launch(void* const* d_in, const int* in_sizes, int n_in,
                              void* d_out, int out_size, void* d_ws, size_t ws_size,
                              hipStream_t stream) {
    (void)in_sizes; (void)n_in; (void)out_size; (void)ws_size;
    const float* x     = (const float*)d_in[0];
    const float* tf    = (const float*)d_in[1];
    const float* gamma = (const float*)d_in[2];
    const float* beta  = (const float*)d_in[3];
    const float* W0 = (const float*)d_in[4];
    const float* b0 = (const float*)d_in[5];
    const float* W1 = (const float*)d_in[6];
    const float* b1 = (const float*)d_in[7];
    const float* W2 = (const float*)d_in[8];
    const float* b2 = (const float*)d_in[9];

    char* ws = (char*)d_ws;
    float* scale  = (float*)(ws);                 // 24576 B
    float* shift  = (float*)(ws + 24576);         // 24576 B
    float* tcb    = (float*)(ws + 49152);         // 24576 B
    short* Wt     = (short*)(ws + 73728);         // 393216 B
    short* hnT    = (short*)(ws + 466944);        // 4 MiB
    short* qb     = (short*)(ws + 4661248);       // 4 MiB
    short* kb     = (short*)(ws + 8855552);       // 4 MiB
    short* vb     = (short*)(ws + 13049856);      // 4 MiB
    float* outp   = (float*)d_out;

    int mb = 0;
    hipError_t qe = hipOccupancyMaxActiveBlocksPerMultiprocessor(&mb, fused_kernel, 256, 0);
    hipError_t le = hipErrorUnknown;
    if (qe == hipSuccess && mb >= 1) {
        int gridN = (mb >= 2) ? 512 : 256;
        void* args[] = { (void*)&x, (void*)&tf, (void*)&gamma, (void*)&beta,
                         (void*)&W0, (void*)&b0, (void*)&W1, (void*)&b1,
                         (void*)&W2, (void*)&b2,
                         (void*)&scale, (void*)&shift, (void*)&tcb, (void*)&Wt,
                         (void*)&hnT, (void*)&qb, (void*)&kb, (void*)&vb,
                         (void*)&outp };
        le = hipLaunchCooperativeKernel((const void*)fused_kernel, dim3(gridN),
                                        dim3(256), args, 0, stream);
    }
    if (le != hipSuccess) {
        // proven 4-kernel fallback
        hipLaunchKernelGGL(gn_kernel, dim3(256), dim3(256), 0, stream,
                           x, tf, gamma, beta, scale, shift, tcb);
        hipLaunchKernelGGL(prep_kernel, dim3(652), dim3(256), 0, stream,
                           x, tf, scale, shift, W0, W1, W2, hnT, Wt, tcb);
        hipLaunchKernelGGL(qkv_gemm, dim3(16, 12, BATCH), dim3(256), 0, stream,
                           hnT, Wt, tcb, b0, b1, b2, qb, kb, vb);
        hipLaunchKernelGGL(attn_kernel, dim3(16, 32), dim3(256), 0, stream,
                           qb, kb, vb, x, outp);
    }
}

// Round 4
// 138.249 us; speedup vs baseline: 1.7209x; 1.7209x over previous
//
#include <hip/hip_runtime.h>
#include <math.h>

#define BATCH 8
#define CX 256
#define TC 512
#define CIN 768
#define HW_TOT 1024
#define NH 4
#define CHD 64

typedef __attribute__((ext_vector_type(8))) short short8;
typedef __attribute__((ext_vector_type(4))) short s4v;
typedef __attribute__((ext_vector_type(4))) float floatx4;
typedef __attribute__((ext_vector_type(4))) int int4v;

// softmax scale folded into Q: 0.125 * log2(e)
#define QSCALE 0.18033688f

// round-to-nearest-even f32 -> bf16
static __device__ __forceinline__ short f2bf(float f) {
    union { float f; unsigned u; } c; c.f = f;
    unsigned r = (c.u + 0x7fffu + ((c.u >> 16) & 1u)) >> 16;
    return (short)r;
}

// truncating pack of two f32 -> two bf16 in one int (lo in low half)
static __device__ __forceinline__ int pack_trunc(float lo, float hi) {
    union { float f; unsigned u; } L, H;
    L.f = lo; H.f = hi;
    return (int)((H.u & 0xffff0000u) | (L.u >> 16));
}

// ---------------------------------------------------------------------------
// Kernel 1: GroupNorm stats -> per-(b,c) scale/shift. NOW 512 threads
// (8 waves/CU instead of 4; each wave covers 3 channels instead of 6).
// Grid 256 x 512.
// ---------------------------------------------------------------------------
__global__ __launch_bounds__(512)
void gn_kernel(const float* __restrict__ x, const float* __restrict__ tf,
               const float* __restrict__ gamma, const float* __restrict__ beta,
               float* __restrict__ scale, float* __restrict__ shift,
               float* __restrict__ tc) {
    const int b = blockIdx.x >> 5;
    const int g = blockIdx.x & 31;
    const int t = threadIdx.x;
    const int w = t >> 6, lane = t & 63;
    if (blockIdx.x < 12) tc[blockIdx.x * 512 + t] = 0.f;   // 6144 floats

    float s = 0.f, ss = 0.f;
    #pragma unroll
    for (int rr = 0; rr < 3; rr++) {
        const int row = w * 3 + rr;          // 0..23
        const int cg = g * 24 + row;
        if (cg < CX) {
            const float4* p = (const float4*)(x + ((size_t)b * CX + cg) * HW_TOT);
            #pragma unroll
            for (int i = 0; i < 4; i++) {
                float4 v = p[lane + 64 * i];
                s += v.x + v.y + v.z + v.w;
                ss += v.x * v.x + v.y * v.y + v.z * v.z + v.w * v.w;
            }
        } else {
            float v = tf[b * TC + cg - CX];
            s += 16.f * v;
            ss += 16.f * v * v;
        }
    }
    #pragma unroll
    for (int d = 1; d < 64; d <<= 1) {
        s += __shfl_xor(s, d);
        ss += __shfl_xor(ss, d);
    }
    __shared__ float rs_[8], rss_[8];
    if (lane == 0) { rs_[w] = s; rss_[w] = ss; }
    __syncthreads();
    float S = 0.f, SS = 0.f;
    #pragma unroll
    for (int i = 0; i < 8; i++) { S += rs_[i]; SS += rss_[i]; }
    const float inv_n = 1.f / (24 * 1024);
    const float mean = S * inv_n;
    const float var = SS * inv_n - mean * mean;
    const float r = rsqrtf(var + 1e-6f);
    if (t < 24) {
        int cg = g * 24 + t;
        float sc = gamma[cg] * r;
        scale[b * CIN + cg] = sc;
        shift[b * CIN + cg] = beta[cg] - mean * sc;
    }
}

// ---------------------------------------------------------------------------
// Kernel 2: merged prep: hnT transpose (blocks 0-255), W transpose (256-267),
// text contribution K-split x4 via atomicAdd (268-651). (unchanged, proven)
// ---------------------------------------------------------------------------
__global__ __launch_bounds__(256)
void prep_kernel(const float* __restrict__ x, const float* __restrict__ tf,
                 const float* __restrict__ scale, const float* __restrict__ shift,
                 const float* __restrict__ W0, const float* __restrict__ W1,
                 const float* __restrict__ W2,
                 short* __restrict__ hnT, short* __restrict__ Wt,
                 float* __restrict__ tc) {
    __shared__ float hs[128];
    __shared__ float red[4][64];
    const int bx = blockIdx.x;
    const int t = threadIdx.x;
    if (bx < 256) {
        int id = (bx & 31) * 256 + t;
        int b = id >> 10;
        const float* xb = x + (size_t)b * CX * HW_TOT + (id & 1023);
        const float* scb = scale + b * CIN;
        const float* shb = shift + b * CIN;
        short* outp = hnT + (size_t)id * CX;
        int c0base = (bx >> 5) * 32;
        for (int c0 = c0base; c0 < c0base + 32; c0 += 8) {
            short8 o;
            #pragma unroll
            for (int i = 0; i < 8; i++) {
                float v = xb[(size_t)(c0 + i) * HW_TOT];
                o[i] = f2bf(v * scb[c0 + i] + shb[c0 + i]);
            }
            *(short8*)(outp + c0) = o;
        }
    } else if (bx < 268) {
        int m = bx - 256;
        int dg = (m % 3) * 256 + t;
        int which = dg >> 8, d = dg & 255;
        const float* Wm = (which == 0) ? W0 : (which == 1) ? W1 : W2;
        int c0base = (m / 3) * 64;
        for (int c0 = c0base; c0 < c0base + 64; c0 += 8) {
            short8 o;
            #pragma unroll
            for (int i = 0; i < 8; i++) o[i] = f2bf(Wm[(size_t)(c0 + i) * CX + d]);
            *(short8*)(Wt + (size_t)dg * CX + c0) = o;
        }
    } else {
        // text contribution, K-split: block handles 128 of the 512 text rows
        int m = bx - 268;
        int ks = m & 3;
        int b = (m >> 2) & 7, dt = m >> 5;          // dt 0..11
        int which = dt >> 2, d0 = (dt & 3) * 64;
        const float* Wm = (which == 0) ? W0 : (which == 1) ? W1 : W2;
        if (t < 128) {
            int c = ks * 128 + t;
            hs[t] = tf[b * TC + c] * scale[b * CIN + CX + c] + shift[b * CIN + CX + c];
        }
        __syncthreads();
        int td = t & 63, tq = t >> 6;
        float acc = 0.f;
        const float* wp = Wm + (size_t)(CX + ks * 128 + tq * 32) * CX + d0 + td;
        #pragma unroll 8
        for (int c = 0; c < 32; c++)
            acc = fmaf(hs[tq * 32 + c], wp[(size_t)c * CX], acc);
        red[tq][td] = acc;
        __syncthreads();
        if (t < 64)
            atomicAdd(&tc[b * CIN + which * CX + d0 + t],
                      red[0][t] + red[1][t] + red[2][t] + red[3][t]);
    }
}

// ---------------------------------------------------------------------------
// Kernel 3: MFMA QKV GEMM, 64x64 tiles, BK=256 single-stage, XOR swizzle
// (round-1 version, proven). Grid (16, 12, 8) x 256.
// ---------------------------------------------------------------------------
__global__ __launch_bounds__(256, 2)
void qkv_gemm(const short* __restrict__ hnT, const short* __restrict__ Wt,
              const float* __restrict__ tc,
              const float* __restrict__ b0, const float* __restrict__ b1,
              const float* __restrict__ b2,
              short* __restrict__ qb, short* __restrict__ kb, short* __restrict__ vb) {
    const int hw0 = blockIdx.x * 64, dt = blockIdx.y, b = blockIdx.z;
    const int which = dt >> 2;
    const int col0 = (dt & 3) * 64;
    const int dg0 = which * 256 + col0;
    const bool OV = (which == 2);

    __shared__ short At[64 * 256];   // 32 KB, row stride 512B, XOR-swizzled
    __shared__ short Bt[64 * 256];   // 32 KB

    const int t = threadIdx.x;
    const int w = t >> 6, l = t & 63;
    const int wm = w >> 1, wn = w & 1;
    const int l15 = l & 15, q = l >> 4;
    const int srow = t >> 2;           // 0..63
    const int cbase = (t & 3) * 8;     // first 16B-chunk of the 8 staged
    const int sw = srow & 7;           // swizzle key

    const short* gA = hnT + (size_t)(b * HW_TOT + hw0 + srow) * CX + cbase * 8;
    const short* gB = Wt + (size_t)(dg0 + srow) * CX + cbase * 8;

    short8 ra[8], rb[8];
    #pragma unroll
    for (int i = 0; i < 8; i++) ra[i] = *(const short8*)(gA + i * 8);
    #pragma unroll
    for (int i = 0; i < 8; i++) rb[i] = *(const short8*)(gB + i * 8);
    short* wA = At + srow * 256;
    short* wB = Bt + srow * 256;
    #pragma unroll
    for (int i = 0; i < 8; i++) *(short8*)(wA + ((cbase + i) ^ sw) * 8) = ra[i];
    #pragma unroll
    for (int i = 0; i < 8; i++) *(short8*)(wB + ((cbase + i) ^ sw) * 8) = rb[i];
    __syncthreads();

    const short* aB = OV ? Bt : At;
    const short* bB = OV ? At : Bt;

    floatx4 acc[2][2] = {};
    __builtin_amdgcn_s_setprio(1);
    #pragma unroll
    for (int kc = 0; kc < 8; kc++) {
        short8 af[2], bf2[2];
        #pragma unroll
        for (int mt = 0; mt < 2; mt++) {
            const int rr = wm * 32 + mt * 16 + l15;
            af[mt] = *(const short8*)(aB + rr * 256 + ((kc * 4 + q) ^ (rr & 7)) * 8);
        }
        #pragma unroll
        for (int nt = 0; nt < 2; nt++) {
            const int rr = wn * 32 + nt * 16 + l15;
            bf2[nt] = *(const short8*)(bB + rr * 256 + ((kc * 4 + q) ^ (rr & 7)) * 8);
        }
        #pragma unroll
        for (int mt = 0; mt < 2; mt++)
            #pragma unroll
            for (int nt = 0; nt < 2; nt++)
                acc[mt][nt] = __builtin_amdgcn_mfma_f32_16x16x32_bf16(
                    af[mt], bf2[nt], acc[mt][nt], 0, 0, 0);
    }
    __builtin_amdgcn_s_setprio(0);

    __syncthreads();
    const float* bias = (which == 0) ? b0 : (which == 1) ? b1 : b2;
    if (!OV) {
        const float qs = (which == 0) ? QSCALE : 1.0f;
        float cadd[2];
        #pragma unroll
        for (int nt = 0; nt < 2; nt++) {
            int d = col0 + wn * 32 + nt * 16 + l15;
            cadd[nt] = bias[d] + tc[b * CIN + which * CX + d];
        }
        #pragma unroll
        for (int mt = 0; mt < 2; mt++)
            #pragma unroll
            for (int rr = 0; rr < 4; rr++)
                #pragma unroll
                for (int nt = 0; nt < 2; nt++)
                    At[(wm * 32 + mt * 16 + q * 4 + rr) * 72 + wn * 32 + nt * 16 + l15]
                        = f2bf((acc[mt][nt][rr] + cadd[nt]) * qs);
    } else {
        #pragma unroll
        for (int mt = 0; mt < 2; mt++)
            #pragma unroll
            for (int rr = 0; rr < 4; rr++) {
                int d = col0 + wm * 32 + mt * 16 + q * 4 + rr;
                float radd = bias[d] + tc[b * CIN + 2 * CX + d];
                #pragma unroll
                for (int nt = 0; nt < 2; nt++)
                    At[(wm * 32 + mt * 16 + q * 4 + rr) * 72 + wn * 32 + nt * 16 + l15]
                        = f2bf(acc[mt][nt][rr] + radd);
            }
    }
    __syncthreads();
    const int sch2 = (t & 3) * 16;
    short8 v0 = *(const short8*)(At + srow * 72 + sch2);
    short8 v1 = *(const short8*)(At + srow * 72 + sch2 + 8);
    if (!OV) {
        short* outp = (which == 0) ? qb : kb;
        size_t off = (size_t)(b * HW_TOT + hw0 + srow) * CX + col0 + sch2;
        *(short8*)(outp + off) = v0;
        *(short8*)(outp + off + 8) = v1;
    } else {
        size_t off = (size_t)(b * CX + col0 + srow) * HW_TOT + hw0 + sch2;
        *(short8*)(vb + off) = v0;
        *(short8*)(vb + off + 8) = v1;
    }
}

// ---------------------------------------------------------------------------
// Kernel 4: flash attention, NOW 8 waves (512 threads) with 4-way j-split:
// wave w: pair = w>>2 owns 32 q-rows, jq = w&3 owns keys [jq*256, jq*256+256)
// processed in 4 jj-iterations of 64 keys. 16 waves/CU (50% occupancy, was
// 25%) and half the barrier rounds. K/V tiles in stride-64 XOR-swizzled LDS
// (layout proven in round-3 fused phase D). Staging: waves 0-3 stage the 4 K
// tiles, waves 4-7 the 4 V tiles. Fixed-max softmax => 4 partials combine by
// addition in a 4-round LDS epilogue. Q frags direct from global (proven).
// Grid (16 qt, 32 bh) x 512.
// ---------------------------------------------------------------------------
__global__ __launch_bounds__(512, 4)
void attn_kernel(const short* __restrict__ qb, const short* __restrict__ kb,
                 const short* __restrict__ vb, const float* __restrict__ x,
                 float* __restrict__ out) {
    __shared__ __align__(16) short SMs[32768];   // K[4] 32 KB | V[4] 32 KB

    const int qt = blockIdx.x, bh = blockIdx.y;
    const int b = bh >> 2, h = bh & 3;
    const int hw0 = qt * 64;

    const int t = threadIdx.x;
    const int w = t >> 6, l = t & 63;
    const int pair = w >> 2;          // q-row half (rows pair*32 .. +31)
    const int jq = w & 3;             // j quarter
    const int l15 = l & 15, q = l >> 4;
    const int t256 = t & 255;
    const int srow = t256 >> 2, sch = (t256 & 3) * 16;
    const int sw7 = srow & 7;
    const int kc0 = (t256 & 3) * 2;
    const int vpos0 = ((sch >> 5) << 5) + ((sch >> 4) & 1) * 4;
    const int vc0 = vpos0 >> 3, voff = vpos0 & 7;
    const bool grpA = (t < 256);      // waves 0-3 stage K; 4-7 stage V

    // Q fragments direct from global
    short8 aq[2][2];
    #pragma unroll
    for (int g = 0; g < 2; g++) {
        const short* gq = qb + (size_t)(b * HW_TOT + hw0 + pair * 32 + g * 16 + l15) * CX
                          + h * CHD + q * 8;
        aq[g][0] = *(const short8*)gq;
        aq[g][1] = *(const short8*)(gq + 32);
    }

    // initial stage (jj = 0) of all 4 quarters
    short8 pf[4][2];
    if (grpA) {
        #pragma unroll
        for (int s = 0; s < 4; s++) {
            const short* gk = kb + (size_t)(b * HW_TOT + s * 256 + srow) * CX + h * CHD + sch;
            pf[s][0] = *(const short8*)gk;
            pf[s][1] = *(const short8*)(gk + 8);
        }
        #pragma unroll
        for (int s = 0; s < 4; s++) {
            short* Ksp = SMs + s * 4096 + srow * 64;
            *(short8*)(Ksp + ((kc0    ) ^ sw7) * 8) = pf[s][0];
            *(short8*)(Ksp + ((kc0 + 1) ^ sw7) * 8) = pf[s][1];
        }
    } else {
        #pragma unroll
        for (int s = 0; s < 4; s++) {
            const short* gv = vb + (size_t)(b * CX + h * CHD + srow) * HW_TOT + s * 256 + sch;
            pf[s][0] = *(const short8*)gv;
            pf[s][1] = *(const short8*)(gv + 8);
        }
        #pragma unroll
        for (int s = 0; s < 4; s++) {
            short* Vsp = SMs + 16384 + s * 4096 + srow * 64;
            *(s4v*)(Vsp + ((vc0    ) ^ sw7) * 8 + voff) = __builtin_shufflevector(pf[s][0], pf[s][0], 0, 1, 2, 3);
            *(s4v*)(Vsp + ((vc0 + 1) ^ sw7) * 8 + voff) = __builtin_shufflevector(pf[s][0], pf[s][0], 4, 5, 6, 7);
            *(s4v*)(Vsp + ((vc0 + 2) ^ sw7) * 8 + voff) = __builtin_shufflevector(pf[s][1], pf[s][1], 0, 1, 2, 3);
            *(s4v*)(Vsp + ((vc0 + 3) ^ sw7) * 8 + voff) = __builtin_shufflevector(pf[s][1], pf[s][1], 4, 5, 6, 7);
        }
    }
    __syncthreads();

    union { int4v i; short8 s; } ones;
    ones.i[0] = 0x3f803f80; ones.i[1] = 0x3f803f80;
    ones.i[2] = 0x3f803f80; ones.i[3] = 0x3f803f80;

    floatx4 oacc[2][4] = {};
    floatx4 lacc[2] = {};
    const short* Kc = SMs + jq * 4096;
    const short* Vc = SMs + 16384 + jq * 4096;

    for (int jj = 0; jj < 4; jj++) {
        if (jj < 3) {   // prefetch next 64-key slab of every quarter
            if (grpA) {
                #pragma unroll
                for (int s = 0; s < 4; s++) {
                    const short* gk = kb + (size_t)(b * HW_TOT + s * 256 + (jj + 1) * 64 + srow) * CX + h * CHD + sch;
                    pf[s][0] = *(const short8*)gk;
                    pf[s][1] = *(const short8*)(gk + 8);
                }
            } else {
                #pragma unroll
                for (int s = 0; s < 4; s++) {
                    const short* gv = vb + (size_t)(b * CX + h * CHD + srow) * HW_TOT + s * 256 + (jj + 1) * 64 + sch;
                    pf[s][0] = *(const short8*)gv;
                    pf[s][1] = *(const short8*)(gv + 8);
                }
            }
        }

        // S^T = K . Q'^T
        floatx4 sacc[2][4] = {};
        __builtin_amdgcn_s_setprio(1);
        #pragma unroll
        for (int nt = 0; nt < 4; nt++) {
            const int r = nt * 16 + l15;
            short8 kf0 = *(const short8*)(Kc + r * 64 + ((q    ) ^ (r & 7)) * 8);
            short8 kf1 = *(const short8*)(Kc + r * 64 + ((4 + q) ^ (r & 7)) * 8);
            #pragma unroll
            for (int g = 0; g < 2; g++) {
                sacc[g][nt] = __builtin_amdgcn_mfma_f32_16x16x32_bf16(kf0, aq[g][0], sacc[g][nt], 0, 0, 0);
                sacc[g][nt] = __builtin_amdgcn_mfma_f32_16x16x32_bf16(kf1, aq[g][1], sacc[g][nt], 0, 0, 0);
            }
        }
        __builtin_amdgcn_s_setprio(0);

        // p = exp2(s'); truncating pack into B-operand registers
        union { int4v i; short8 s; } uu[2][2];
        #pragma unroll
        for (int g = 0; g < 2; g++)
            #pragma unroll
            for (int nt = 0; nt < 4; nt++) {
                float e0 = exp2f(sacc[g][nt][0]);
                float e1 = exp2f(sacc[g][nt][1]);
                float e2 = exp2f(sacc[g][nt][2]);
                float e3 = exp2f(sacc[g][nt][3]);
                uu[g][nt >> 1].i[(nt & 1) * 2]     = pack_trunc(e0, e1);
                uu[g][nt >> 1].i[(nt & 1) * 2 + 1] = pack_trunc(e2, e3);
            }

        __builtin_amdgcn_s_setprio(1);
        // l += 1^T . P
        #pragma unroll
        for (int g = 0; g < 2; g++) {
            lacc[g] = __builtin_amdgcn_mfma_f32_16x16x32_bf16(ones.s, uu[g][0].s, lacc[g], 0, 0, 0);
            lacc[g] = __builtin_amdgcn_mfma_f32_16x16x32_bf16(ones.s, uu[g][1].s, lacc[g], 0, 0, 0);
        }

        // O^T += V^T . P
        #pragma unroll
        for (int ct = 0; ct < 4; ct++) {
            const int rv = ct * 16 + l15;
            #pragma unroll
            for (int kcc = 0; kcc < 2; kcc++) {
                short8 vf = *(const short8*)(Vc + rv * 64 + ((kcc * 4 + q) ^ (rv & 7)) * 8);
                #pragma unroll
                for (int g = 0; g < 2; g++)
                    oacc[g][ct] = __builtin_amdgcn_mfma_f32_16x16x32_bf16(
                        vf, uu[g][kcc].s, oacc[g][ct], 0, 0, 0);
            }
        }
        __builtin_amdgcn_s_setprio(0);

        if (jj < 3) {
            __syncthreads();   // all waves done reading current tiles
            if (grpA) {
                #pragma unroll
                for (int s = 0; s < 4; s++) {
                    short* Ksp = SMs + s * 4096 + srow * 64;
                    *(short8*)(Ksp + ((kc0    ) ^ sw7) * 8) = pf[s][0];
                    *(short8*)(Ksp + ((kc0 + 1) ^ sw7) * 8) = pf[s][1];
                }
            } else {
                #pragma unroll
                for (int s = 0; s < 4; s++) {
                    short* Vsp = SMs + 16384 + s * 4096 + srow * 64;
                    *(s4v*)(Vsp + ((vc0    ) ^ sw7) * 8 + voff) = __builtin_shufflevector(pf[s][0], pf[s][0], 0, 1, 2, 3);
                    *(s4v*)(Vsp + ((vc0 + 1) ^ sw7) * 8 + voff) = __builtin_shufflevector(pf[s][0], pf[s][0], 4, 5, 6, 7);
                    *(s4v*)(Vsp + ((vc0 + 2) ^ sw7) * 8 + voff) = __builtin_shufflevector(pf[s][1], pf[s][1], 0, 1, 2, 3);
                    *(s4v*)(Vsp + ((vc0 + 3) ^ sw7) * 8 + voff) = __builtin_shufflevector(pf[s][1], pf[s][1], 4, 5, 6, 7);
                }
            }
            __syncthreads();   // writes visible
        }
    }

    // 4-way combine through LDS (fixed-max => pure addition), rounds by jq.
    __syncthreads();
    float* Of = (float*)SMs;                 // [qi][c] stride 68 (17408 B)
    float* Lf = ((float*)SMs) + 64 * 68;     // [qi] (256 B)
    if (jq == 3) {
        #pragma unroll
        for (int g = 0; g < 2; g++) {
            int qi = pair * 32 + g * 16 + l15;
            #pragma unroll
            for (int ct = 0; ct < 4; ct++)
                *(floatx4*)&Of[qi * 68 + ct * 16 + q * 4] = oacc[g][ct];
            if (q == 0) Lf[qi] = lacc[g][0];
        }
    }
    __syncthreads();
    if (jq == 2) {
        #pragma unroll
        for (int g = 0; g < 2; g++) {
            int qi = pair * 32 + g * 16 + l15;
            #pragma unroll
            for (int ct = 0; ct < 4; ct++) {
                floatx4 po = *(const floatx4*)&Of[qi * 68 + ct * 16 + q * 4];
                *(floatx4*)&Of[qi * 68 + ct * 16 + q * 4] = po + oacc[g][ct];
            }
            if (q == 0) Lf[qi] += lacc[g][0];
        }
    }
    __syncthreads();
    if (jq == 1) {
        #pragma unroll
        for (int g = 0; g < 2; g++) {
            int qi = pair * 32 + g * 16 + l15;
            #pragma unroll
            for (int ct = 0; ct < 4; ct++) {
                floatx4 po = *(const floatx4*)&Of[qi * 68 + ct * 16 + q * 4];
                *(floatx4*)&Of[qi * 68 + ct * 16 + q * 4] = po + oacc[g][ct];
            }
            if (q == 0) Lf[qi] += lacc[g][0];
        }
    }
    __syncthreads();
    if (jq == 0) {
        #pragma unroll
        for (int g = 0; g < 2; g++) {
            int qi = pair * 32 + g * 16 + l15;
            const float rinv = 1.f / (lacc[g][0] + Lf[qi]);
            #pragma unroll
            for (int ct = 0; ct < 4; ct++) {
                floatx4 po = *(const floatx4*)&Of[qi * 68 + ct * 16 + q * 4];
                #pragma unroll
                for (int r = 0; r < 4; r++) {
                    int c = h * CHD + ct * 16 + q * 4 + r;
                    size_t idx = (size_t)(b * CX + c) * HW_TOT + hw0 + qi;
                    out[idx] = x[idx] + (oacc[g][ct][r] + po[r]) * rinv;
                }
            }
        }
    }
}

// ---------------------------------------------------------------------------
extern "C" void kernel_launch(void* const* d_in, const int* in_sizes, int n_in,
                              void* d_out, int out_size, void* d_ws, size_t ws_size,
                              hipStream_t stream) {
    (void)in_sizes; (void)n_in; (void)out_size; (void)ws_size;
    const float* x     = (const float*)d_in[0];
    const float* tf    = (const float*)d_in[1];
    const float* gamma = (const float*)d_in[2];
    const float* beta  = (const float*)d_in[3];
    const float* W0 = (const float*)d_in[4];
    const float* b0 = (const float*)d_in[5];
    const float* W1 = (const float*)d_in[6];
    const float* b1 = (const float*)d_in[7];
    const float* W2 = (const float*)d_in[8];
    const float* b2 = (const float*)d_in[9];

    char* ws = (char*)d_ws;
    float* scale  = (float*)(ws);                 // 24576 B
    float* shift  = (float*)(ws + 24576);         // 24576 B
    float* tcb    = (float*)(ws + 49152);         // 24576 B
    short* Wt     = (short*)(ws + 73728);         // 393216 B
    short* hnT    = (short*)(ws + 466944);        // 4 MiB
    short* qb     = (short*)(ws + 4661248);       // 4 MiB
    short* kb     = (short*)(ws + 8855552);       // 4 MiB
    short* vb     = (short*)(ws + 13049856);      // 4 MiB

    hipLaunchKernelGGL(gn_kernel, dim3(256), dim3(512), 0, stream,
                       x, tf, gamma, beta, scale, shift, tcb);
    hipLaunchKernelGGL(prep_kernel, dim3(652), dim3(256), 0, stream,
                       x, tf, scale, shift, W0, W1, W2, hnT, Wt, tcb);
    hipLaunchKernelGGL(qkv_gemm, dim3(16, 12, BATCH), dim3(256), 0, stream,
                       hnT, Wt, tcb, b0, b1, b2, qb, kb, vb);
    hipLaunchKernelGGL(attn_kernel, dim3(16, 32), dim3(512), 0, stream,
                       qb, kb, vb, x, (float*)d_out);
}